// Round 8
// baseline (3465.871 us; speedup 1.0000x reference)
//
#include <hip/hip_runtime.h>

#define NPLANES 24
#define NBLOCKS 12
#define IMG 192
#define RW 194        // f16 ring stride in halfs = 97 dwords (odd -> conflict-free)
#define TSTEPS 926    // wavefront t = 4*i + j

typedef _Float16 h2v   __attribute__((ext_vector_type(2)));
typedef _Float16 f16x8 __attribute__((ext_vector_type(8)));
typedef float    f32x4 __attribute__((ext_vector_type(4)));
typedef __fp16   fp16x2 __attribute__((ext_vector_type(2)));

__device__ __forceinline__ h2v asH2(float f) { union { float f; h2v h; } u; u.f = f; return u.h; }
__device__ __forceinline__ float fdot2(h2v a, h2v b, float c) {
  return __builtin_amdgcn_fdot2(a, b, c, false);
}
__device__ __forceinline__ h2v pk(float a, float b) {
  union { fp16x2 p; h2v h; } u;
  u.p = __builtin_amdgcn_cvt_pkrtz(a, b);
  return u.h;
}
__device__ __forceinline__ float fast_tanh(float x) {
  float e = __expf(2.0f * x);
  return 1.0f - 2.0f / (e + 1.0f);
}

// lane (0..47) <-> interior row i == lane (mod 48); returns active.
__device__ __forceinline__ bool cellmap(int t, int lane, int& i, int& j) {
  const int i_min = (t <= 185) ? 0 : ((t - 182) >> 2);
  int i_max = t >> 2; if (i_max > 185) i_max = 185;
  const int k48 = (i_min - lane + 47) / 48;   // numerator >= 0 always
  i = lane + 48 * k48;
  j = t - 4 * i;
  return (lane < 48) && (i <= i_max);
}

// One block = TWO planes, 512 threads = 8 waves, software-pipelined:
//  P1: L1(A) [w0-5 MFMA] || L3(B) [w6-7 scalar]
//  P2: L2(A) [w0-5 MFMA] || xbuild(B) [w6] + finalize+dbuild(B) [w7]
//  P3/P4: roles swapped (B on MFMA, A on scalar).
// 2 barriers per plane-step; both wave groups busy every phase.
__launch_bounds__(512)
__global__ void codec_kernel(const float* __restrict__ x,
                             const float* __restrict__ W1g, const float* __restrict__ b1g,
                             const float* __restrict__ W2g, const float* __restrict__ b2g,
                             const float* __restrict__ W3g, const float* __restrict__ b3g,
                             const float* __restrict__ W4g, const float* __restrict__ b4g,
                             float* __restrict__ ws)
{
  __shared__ _Float16 ringH[2][64 * RW];   // 2 x 24832 B, f16 deltas; pad cols 0..2,189..191 = 0
  __shared__ _Float16 featA[2][48 * 72];   // 2 x 6912 B: [cell][48 feat + 16 zero + 8 pad]
  __shared__ _Float16 h1A [2][48 * 104];   // 2 x 9984 B
  __shared__ _Float16 h2A [2][48 * 40];    // 2 x 3840 B
  __shared__ float    p4L [2][48 * 2];     // 2 x 384 B
  __shared__ _Float16 w1B[96 * 72];        // 13824 B  [n][48k + 16 zero + 8 pad]
  __shared__ _Float16 w2B[32 * 104];       //  6656 B
  __shared__ _Float16 w3H[12 * 24];        //   576 B
  __shared__ float    b1L[96], b2L[24], b3L[12], w4F[12], b4L[1];
  // total ~114 KB < 160 KB

  const int tid  = threadIdx.x;
  const int lane = tid & 63;
  const int w    = __builtin_amdgcn_readfirstlane(tid >> 6);
  const int lam  = lane & 15;
  const int quad = lane >> 4;
  const float* __restrict__ xp[2] = {
    x + (size_t)(2 * blockIdx.x + 0) * (IMG * IMG),
    x + (size_t)(2 * blockIdx.x + 1) * (IMG * IMG) };

  // ---- one-time init ----
  { int* rz = (int*)&ringH[0][0];
    for (int u = tid; u < 2 * 64 * RW / 2; u += 512) rz[u] = 0; }
  { int* fz = (int*)&featA[0][0];
    for (int u = tid; u < 2 * 48 * 72 / 2; u += 512) fz[u] = 0; }
  { int* hz = (int*)&h1A[0][0];
    for (int u = tid; u < 2 * 48 * 104 / 2; u += 512) hz[u] = 0; }
  { int* gz = (int*)&h2A[0][0];
    for (int u = tid; u < 2 * 48 * 40 / 2; u += 512) gz[u] = 0; }
  for (int u = tid; u < 2 * 48 * 2; u += 512) p4L[0][u] = 0.f;
  for (int u = tid; u < 96 * 72; u += 512) {
    int n = u / 72, k = u - n * 72;
    w1B[u] = (k < 48) ? (_Float16)W1g[k * 96 + n] : (_Float16)0.f;
  }
  for (int u = tid; u < 32 * 104; u += 512) {
    int n = u / 104, k = u - n * 104;
    w2B[u] = (n < 24 && k < 96) ? (_Float16)W2g[k * 24 + n] : (_Float16)0.f;
  }
  for (int u = tid; u < 12 * 24; u += 512) { int n = u / 24, k = u - n * 24; w3H[u] = (_Float16)W3g[k * 12 + n]; }
  if (tid < 96) b1L[tid] = b1g[tid];
  if (tid < 24) b2L[tid] = b2g[tid];
  if (tid < 12) b3L[tid] = b3g[tid];
  if (tid < 12) w4F[tid] = W4g[tid];
  if (tid == 0) b4L[0] = b4g[0];
  __syncthreads();

  // ---- persistent MFMA B-fragments (loaded once) ----
  f16x8 B1[2] = {}; f16x8 B2[3] = {};
  float bias1 = 0.f, bias2 = 0.f;
  int m2 = 0, n2 = 0;
  if (w < 6) {
    const int n1 = 16 * w + lam;
    B1[0] = *(const f16x8*)&w1B[n1 * 72 + quad * 8];
    B1[1] = *(const f16x8*)&w1B[n1 * 72 + quad * 8 + 32];
    bias1 = b1L[n1];
    m2 = w % 3;
    n2 = 16 * (w / 3) + lam;
    #pragma unroll
    for (int kt = 0; kt < 3; ++kt)
      B2[kt] = *(const f16x8*)&w2B[n2 * 104 + quad * 8 + 32 * kt];
    bias2 = (n2 < 24) ? b2L[n2] : 0.f;
  }

  // per-plane scalar state
  float xw[2][3][7], xl[2][3], xt6[2] = {0.f, 0.f};   // wave 6 windows
  float xt7[2] = {0.f, 0.f};                          // wave 7 targets
  float sumsq = 0.0f;

  // ---- stage helpers ----
  auto L1 = [&](int P) {
    f32x4 acc0 = {bias1, bias1, bias1, bias1};
    f32x4 acc1 = acc0, acc2 = acc0;
    const f16x8 a00 = *(const f16x8*)&featA[P][(0 * 16 + lam) * 72 + quad * 8];
    const f16x8 a01 = *(const f16x8*)&featA[P][(0 * 16 + lam) * 72 + quad * 8 + 32];
    const f16x8 a10 = *(const f16x8*)&featA[P][(1 * 16 + lam) * 72 + quad * 8];
    const f16x8 a11 = *(const f16x8*)&featA[P][(1 * 16 + lam) * 72 + quad * 8 + 32];
    const f16x8 a20 = *(const f16x8*)&featA[P][(2 * 16 + lam) * 72 + quad * 8];
    const f16x8 a21 = *(const f16x8*)&featA[P][(2 * 16 + lam) * 72 + quad * 8 + 32];
    acc0 = __builtin_amdgcn_mfma_f32_16x16x32_f16(a00, B1[0], acc0, 0, 0, 0);
    acc1 = __builtin_amdgcn_mfma_f32_16x16x32_f16(a10, B1[0], acc1, 0, 0, 0);
    acc2 = __builtin_amdgcn_mfma_f32_16x16x32_f16(a20, B1[0], acc2, 0, 0, 0);
    acc0 = __builtin_amdgcn_mfma_f32_16x16x32_f16(a01, B1[1], acc0, 0, 0, 0);
    acc1 = __builtin_amdgcn_mfma_f32_16x16x32_f16(a11, B1[1], acc1, 0, 0, 0);
    acc2 = __builtin_amdgcn_mfma_f32_16x16x32_f16(a21, B1[1], acc2, 0, 0, 0);
    const int ncol = 16 * w + lam;
    #pragma unroll
    for (int r = 0; r < 4; ++r)
      h1A[P][(0 * 16 + quad * 4 + r) * 104 + ncol] = (_Float16)fast_tanh(acc0[r]);
    #pragma unroll
    for (int r = 0; r < 4; ++r)
      h1A[P][(1 * 16 + quad * 4 + r) * 104 + ncol] = (_Float16)fast_tanh(acc1[r]);
    #pragma unroll
    for (int r = 0; r < 4; ++r)
      h1A[P][(2 * 16 + quad * 4 + r) * 104 + ncol] = (_Float16)fast_tanh(acc2[r]);
  };

  auto L2 = [&](int P) {
    f32x4 acc = {bias2, bias2, bias2, bias2};
    const f16x8 c0 = *(const f16x8*)&h1A[P][(m2 * 16 + lam) * 104 + quad * 8];
    const f16x8 c1 = *(const f16x8*)&h1A[P][(m2 * 16 + lam) * 104 + quad * 8 + 32];
    const f16x8 c2 = *(const f16x8*)&h1A[P][(m2 * 16 + lam) * 104 + quad * 8 + 64];
    acc = __builtin_amdgcn_mfma_f32_16x16x32_f16(c0, B2[0], acc, 0, 0, 0);
    acc = __builtin_amdgcn_mfma_f32_16x16x32_f16(c1, B2[1], acc, 0, 0, 0);
    acc = __builtin_amdgcn_mfma_f32_16x16x32_f16(c2, B2[2], acc, 0, 0, 0);
    if (n2 < 24) {
      #pragma unroll
      for (int r = 0; r < 4; ++r)
        h2A[P][(m2 * 16 + quad * 4 + r) * 40 + n2] = (_Float16)fast_tanh(acc[r]);
    }
  };

  auto L3 = [&](int P, int t) {   // waves 6,7: 6 neurons each + L4 partial
    int i, j;
    if (cellmap(t, lane, i, j)) {
      const float4 g0 = *(const float4*)&h2A[P][lane * 40 + 0];
      const float4 g1 = *(const float4*)&h2A[P][lane * 40 + 8];
      const float4 g2 = *(const float4*)&h2A[P][lane * 40 + 16];
      h2v gp[12];
      gp[0] = asH2(g0.x); gp[1] = asH2(g0.y); gp[2]  = asH2(g0.z); gp[3]  = asH2(g0.w);
      gp[4] = asH2(g1.x); gp[5] = asH2(g1.y); gp[6]  = asH2(g1.z); gp[7]  = asH2(g1.w);
      gp[8] = asH2(g2.x); gp[9] = asH2(g2.y); gp[10] = asH2(g2.z); gp[11] = asH2(g2.w);
      const int nb = (w - 6) * 6;
      float p = 0.0f;
      #pragma unroll
      for (int m = 0; m < 6; ++m) {
        const int n = nb + m;
        float a = b3L[n];
        const float4 wv0 = *(const float4*)&w3H[n * 24 + 0];
        const float4 wv1 = *(const float4*)&w3H[n * 24 + 8];
        const float4 wv2 = *(const float4*)&w3H[n * 24 + 16];
        a = fdot2(gp[0], asH2(wv0.x), a);  a = fdot2(gp[1], asH2(wv0.y), a);
        a = fdot2(gp[2], asH2(wv0.z), a);  a = fdot2(gp[3], asH2(wv0.w), a);
        a = fdot2(gp[4], asH2(wv1.x), a);  a = fdot2(gp[5], asH2(wv1.y), a);
        a = fdot2(gp[6], asH2(wv1.z), a);  a = fdot2(gp[7], asH2(wv1.w), a);
        a = fdot2(gp[8], asH2(wv2.x), a);  a = fdot2(gp[9], asH2(wv2.y), a);
        a = fdot2(gp[10], asH2(wv2.z), a); a = fdot2(gp[11], asH2(wv2.w), a);
        p = fmaf(fast_tanh(a), w4F[n], p);
      }
      p4L[P][lane * 2 + (w - 6)] = p;
    }
  };

  auto xbuild = [&](int P, int t) {   // wave 6: x-part features (cols 0..23)
    int i, j;
    if (cellmap(t, lane, i, j)) {
      const float* xrow = xp[P] + i * IMG + j;
      if (j == 0) {
        #pragma unroll
        for (int r = 0; r < 3; ++r)
          #pragma unroll
          for (int c = 0; c < 7; ++c) xw[P][r][c] = xrow[r * IMG + c];
        #pragma unroll
        for (int c = 0; c < 3; ++c) xl[P][c] = xrow[3 * IMG + c];
        xt6[P] = xrow[3 * IMG + 3];
      } else {
        #pragma unroll
        for (int r = 0; r < 3; ++r) {
          #pragma unroll
          for (int c = 0; c < 6; ++c) xw[P][r][c] = xw[P][r][c + 1];
          xw[P][r][6] = xrow[r * IMG + 6];
        }
        xl[P][0] = xl[P][1]; xl[P][1] = xl[P][2]; xl[P][2] = xt6[P];
        xt6[P] = xrow[3 * IMG + 3];
      }
      float fx[24];
      #pragma unroll
      for (int r = 0; r < 3; ++r)
        #pragma unroll
        for (int c = 0; c < 7; ++c) fx[7 * r + c] = xw[P][r][c];
      fx[21] = xl[P][0]; fx[22] = xl[P][1]; fx[23] = xl[P][2];
      union { h2v p[12]; float4 v[3]; } fb;
      #pragma unroll
      for (int q = 0; q < 12; ++q) fb.p[q] = pk(fx[2 * q], fx[2 * q + 1]);
      #pragma unroll
      for (int q = 0; q < 3; ++q)
        *(float4*)&featA[P][lane * 72 + 8 * q] = fb.v[q];
    }
  };

  auto fin = [&](int P, int t) {      // wave 7: finalize step t
    int i, j;
    if (cellmap(t, lane, i, j)) {
      const float2 pp = *(const float2*)&p4L[P][lane * 2];
      const float s = b4L[0] + pp.x + pp.y;
      const float pred = fast_tanh(s);
      const float d = xt7[P] - pred;
      ringH[P][(i & 63) * RW + 3 + j] = (_Float16)d;
      sumsq += d * d;
    }
  };

  auto dbuild = [&](int P, int t) {   // wave 7: delta-part features (cols 24..47) + target load
    int i, j;
    if (cellmap(t, lane, i, j)) {
      xt7[P] = xp[P][(i + 3) * IMG + (j + 3)];   // latency hidden to next phase
      union { _Float16 h[24]; float4 v[3]; } tb;
      const int b0 = ((i - 3) & 63) * RW + j;
      const int b1 = ((i - 2) & 63) * RW + j;
      const int b2 = ((i - 1) & 63) * RW + j;
      const int b3 = (i & 63) * RW + j;
      #pragma unroll
      for (int d = 0; d < 7; ++d) tb.h[d]      = ringH[P][b0 + d];
      #pragma unroll
      for (int d = 0; d < 7; ++d) tb.h[7 + d]  = ringH[P][b1 + d];
      #pragma unroll
      for (int d = 0; d < 7; ++d) tb.h[14 + d] = ringH[P][b2 + d];
      #pragma unroll
      for (int d = 0; d < 3; ++d) tb.h[21 + d] = ringH[P][b3 + d];
      #pragma unroll
      for (int q = 0; q < 3; ++q)
        *(float4*)&featA[P][lane * 72 + 24 + 8 * q] = tb.v[q];
    }
  };

  // ---- prime plane A step 0 ----
  if (w == 6) xbuild(0, 0);
  if (w == 7) dbuild(0, 0);
  __syncthreads();

  // ---- pipelined main loop: each k = one step of A and one of B ----
  for (int k = 0; k <= TSTEPS; ++k) {
    #pragma unroll
    for (int half = 0; half < 2; ++half) {
      const int P = half;          // MFMA plane this half
      const int Q = 1 - half;      // scalar plane this half
      const int t3 = half ? k : k - 1;       // L3 step for Q
      const int tf = half ? k : k - 1;       // finalize step for Q
      const int tb = half ? k + 1 : k;       // build step for Q

      // phase odd: MFMA L1(P,k) || scalar L3(Q,t3)
      if (w < 6) { if (k < TSTEPS) L1(P); }
      else       { if (t3 >= 0 && t3 < TSTEPS) L3(Q, t3); }
      __syncthreads();

      // phase even: MFMA L2(P,k) || xbuild(Q,tb) [w6] / fin(Q,tf)+dbuild(Q,tb) [w7]
      if (w < 6)       { if (k < TSTEPS) L2(P); }
      else if (w == 6) { if (tb < TSTEPS) xbuild(Q, tb); }
      else             { if (tf >= 0 && tf < TSTEPS) fin(Q, tf);
                         if (tb < TSTEPS) dbuild(Q, tb); }
      __syncthreads();
    }
  }

  // wave 7 holds sumsq for both planes
  if (w == 7) {
    #pragma unroll
    for (int off = 32; off >= 1; off >>= 1)
      sumsq += __shfl_down(sumsq, off);
    if (lane == 0) ws[blockIdx.x] = sumsq;
  }
}

__global__ void finalize_kernel(const float* __restrict__ ws, float* __restrict__ out) {
  if (threadIdx.x == 0) {
    float s = 0.0f;
    #pragma unroll
    for (int p = 0; p < NBLOCKS; ++p) s += ws[p];
    out[0] = sqrtf(s / 875520.0f);   // b*c*(h-2)*w = 8*3*190*192
  }
}

extern "C" void kernel_launch(void* const* d_in, const int* in_sizes, int n_in,
                              void* d_out, int out_size, void* d_ws, size_t ws_size,
                              hipStream_t stream) {
  (void)in_sizes; (void)n_in; (void)out_size; (void)ws_size;
  const float* x  = (const float*)d_in[0];
  const float* W1 = (const float*)d_in[1];
  const float* b1 = (const float*)d_in[2];
  const float* W2 = (const float*)d_in[3];
  const float* b2 = (const float*)d_in[4];
  const float* W3 = (const float*)d_in[5];
  const float* b3 = (const float*)d_in[6];
  const float* W4 = (const float*)d_in[7];
  const float* b4 = (const float*)d_in[8];
  float* ws = (float*)d_ws;

  codec_kernel<<<NBLOCKS, 512, 0, stream>>>(x, W1, b1, W2, b2, W3, b3, W4, b4, ws);
  finalize_kernel<<<1, 64, 0, stream>>>(ws, (float*)d_out);
}

// Round 9
// 2443.735 us; speedup vs baseline: 1.4183x; 1.4183x over previous
//
#include <hip/hip_runtime.h>

#define NPLANES 24
#define IMG 192
#define RW 194        // f16 ring stride in halfs (388B); addr col = 3 + delta-col
#define TSTEPS 926    // wavefront t = 4*i + j

typedef _Float16 h2v   __attribute__((ext_vector_type(2)));
typedef _Float16 f16x8 __attribute__((ext_vector_type(8)));
typedef float    f32x4 __attribute__((ext_vector_type(4)));
typedef __fp16   fp16x2 __attribute__((ext_vector_type(2)));

__device__ __forceinline__ h2v pk(float a, float b) {
  union { fp16x2 p; h2v h; } u;
  u.p = __builtin_amdgcn_cvt_pkrtz(a, b);
  return u.h;
}
__device__ __forceinline__ float fast_tanh(float x) {
  float e = __expf(2.0f * x);
  return 1.0f - 2.0f / (e + 1.0f);
}

// One block per plane, 192 threads = 3 waves, ONE barrier per step.
// Wave w owns cells 16w..16w+15 (cell slot = row i mod 48) and runs the whole
// per-step pipeline in-wave: build -> L1 (12 MFMA) -> L2 (6 MFMA) -> L3
// (1 MFMA, K/N zero-padded) -> L4 (shfl_xor butterfly) -> delta -> ring.
// All weights persistent in VGPRs (B-frags); only cross-wave dependency is the
// delta ring (rows i-1..i-3 cross 16-cell boundaries) -> single __syncthreads.
__launch_bounds__(192)
__global__ void codec_kernel(const float* __restrict__ x,
                             const float* __restrict__ W1g, const float* __restrict__ b1g,
                             const float* __restrict__ W2g, const float* __restrict__ b2g,
                             const float* __restrict__ W3g, const float* __restrict__ b3g,
                             const float* __restrict__ W4g, const float* __restrict__ b4g,
                             float* __restrict__ ws)
{
  __shared__ _Float16 ringH[64 * RW];   // 24832 B f16 deltas; cols 0..2 & >=189 stay 0
  __shared__ _Float16 featA[48 * 72];   //  6912 B [cell][48 feat | 16 ZERO (K-pad) | 8 scratch]
  __shared__ _Float16 h1A  [48 * 104];  //  9984 B [cell][96 + pad]
  __shared__ _Float16 h2A  [48 * 40];   //  3840 B [cell][24 real + 8 ZERO (K-pad) + 8 pad]
  __shared__ _Float16 w1B  [96 * 72];   // 13824 B [n][48 k + zero pad]
  __shared__ _Float16 w2B  [32 * 104];  //  6656 B [n pad32][96 k + pad]
  __shared__ _Float16 w3B  [16 * 32];   //  1024 B [n pad16][24 k + zero pad]
  __shared__ float    p4L  [48];
  __shared__ float    b1L[96], b2L[24], b3L[16], w4F[16], b4L[1];
  __shared__ float    wsum[3];
  // ~68 KB LDS

  const int tid  = threadIdx.x;          // 0..191
  const int lane = tid & 63;
  const int w    = __builtin_amdgcn_readfirstlane(tid >> 6);   // wave 0..2
  const int lam  = lane & 15;
  const int quad = lane >> 4;
  const int cell = 16 * w + lam;         // this lane's cell slot (same across quads)
  const float* __restrict__ xp = x + (size_t)blockIdx.x * (IMG * IMG);

  // ---- one-time init ----
  { unsigned* z = (unsigned*)ringH; for (int u = tid; u < 64 * RW / 2;  u += 192) z[u] = 0; }
  { unsigned* z = (unsigned*)featA; for (int u = tid; u < 48 * 72 / 2;  u += 192) z[u] = 0; }
  { unsigned* z = (unsigned*)h1A;   for (int u = tid; u < 48 * 104 / 2; u += 192) z[u] = 0; }
  { unsigned* z = (unsigned*)h2A;   for (int u = tid; u < 48 * 40 / 2;  u += 192) z[u] = 0; }
  for (int u = tid; u < 96 * 72; u += 192) {
    int n = u / 72, k = u - n * 72;
    w1B[u] = (k < 48) ? (_Float16)W1g[k * 96 + n] : (_Float16)0.f;
  }
  for (int u = tid; u < 32 * 104; u += 192) {
    int n = u / 104, k = u - n * 104;
    w2B[u] = (n < 24 && k < 96) ? (_Float16)W2g[k * 24 + n] : (_Float16)0.f;
  }
  for (int u = tid; u < 16 * 32; u += 192) {
    int n = u / 32, k = u - n * 32;
    w3B[u] = (n < 12 && k < 24) ? (_Float16)W3g[k * 12 + n] : (_Float16)0.f;
  }
  for (int u = tid; u < 96; u += 192) b1L[u] = b1g[u];
  if (tid < 24) b2L[tid] = b2g[tid];
  if (tid < 16) b3L[tid] = (tid < 12) ? b3g[tid] : 0.f;
  if (tid < 16) w4F[tid] = (tid < 12) ? W4g[tid] : 0.f;
  if (tid == 0) b4L[0] = b4g[0];
  __syncthreads();

  // ---- persistent weight fragments (loaded ONCE into VGPRs) ----
  f16x8 B1[6][2], B2[2][3], B3;
  float bias1v[6], bias2v[2];
  #pragma unroll
  for (int nt = 0; nt < 6; ++nt) {
    #pragma unroll
    for (int kt = 0; kt < 2; ++kt)
      B1[nt][kt] = *(const f16x8*)&w1B[(16 * nt + lam) * 72 + quad * 8 + 32 * kt];
    bias1v[nt] = b1L[16 * nt + lam];
  }
  #pragma unroll
  for (int nt = 0; nt < 2; ++nt) {
    #pragma unroll
    for (int kt = 0; kt < 3; ++kt)
      B2[nt][kt] = *(const f16x8*)&w2B[(16 * nt + lam) * 104 + quad * 8 + 32 * kt];
    bias2v[nt] = (16 * nt + lam < 24) ? b2L[16 * nt + lam] : 0.f;
  }
  B3 = *(const f16x8*)&w3B[lam * 32 + quad * 8];
  const float bias3v = b3L[lam];    // padded (0 for lam>=12)
  const float w4v   = w4F[lam];     // padded
  const float b4v   = b4L[0];

  float xw[3][7], xl4[4];           // quad-0 sliding x-window (regs)
  float sumsq = 0.0f;

  for (int t = 0; t < TSTEPS; ++t) {
    const int i_min = (t <= 185) ? 0 : ((t - 182) >> 2);
    int i_max = t >> 2; if (i_max > 185) i_max = 185;
    const int k48 = (i_min - cell + 47) / 48;      // >= 0 always
    const int i = cell + 48 * k48;
    const bool active = (i <= i_max);
    const int j = t - 4 * i;

    // ================= build (quad-parallel, in-wave) =================
    if (active) {
      if (quad == 0) {
        const float* xrow = xp + i * IMG + j;
        if (j == 0) {                               // row activation: cold load
          #pragma unroll
          for (int r = 0; r < 3; ++r)
            #pragma unroll
            for (int c = 0; c < 7; ++c) xw[r][c] = xrow[r * IMG + c];
          #pragma unroll
          for (int c = 0; c < 4; ++c) xl4[c] = xrow[3 * IMG + c];
        } else {                                    // slide right one column
          #pragma unroll
          for (int r = 0; r < 3; ++r) {
            #pragma unroll
            for (int c = 0; c < 6; ++c) xw[r][c] = xw[r][c + 1];
            xw[r][6] = xrow[r * IMG + 6];
          }
          xl4[0] = xl4[1]; xl4[1] = xl4[2]; xl4[2] = xl4[3];
          xl4[3] = xrow[3 * IMG + 3];
        }
        // pack x-part features f0..f23
        union { h2v p[12]; float4 v[3]; } fb;
        #pragma unroll
        for (int r = 0; r < 3; ++r) {
          fb.p[4 * r + 0] = pk(xw[r][0], xw[r][1]);
          fb.p[4 * r + 1] = pk(xw[r][2], xw[r][3]);
          fb.p[4 * r + 2] = pk(xw[r][4], xw[r][5]);
          fb.p[4 * r + 3] = pk(xw[r][6], xw[(r + 1) % 3][0]);  // placeholder fix below
        }
        // NOTE: row-major f: f[7r+c]; build pairs explicitly instead:
        float fx[24];
        #pragma unroll
        for (int r = 0; r < 3; ++r)
          #pragma unroll
          for (int c = 0; c < 7; ++c) fx[7 * r + c] = xw[r][c];
        fx[21] = xl4[0]; fx[22] = xl4[1]; fx[23] = xl4[2];
        #pragma unroll
        for (int q = 0; q < 12; ++q) fb.p[q] = pk(fx[2 * q], fx[2 * q + 1]);
        #pragma unroll
        for (int q = 0; q < 3; ++q)
          *(float4*)&featA[cell * 72 + 8 * q] = fb.v[q];
      }
      // uniform 7-tap ring gather: quad1->row i-3 (f24..30), quad2->row i-2
      // (f31..37), quad3->row i-1 (f38..44), quad0->row i (f45..47 + scratch)
      const int rowOff = (quad == 0) ? 0 : (quad - 4);
      const int base = ((i + rowOff) & 63) * RW + j;
      #pragma unroll
      for (int u = 0; u < 7; ++u) {
        const _Float16 v = ringH[base + u];
        const int dst = (quad == 0) ? ((u < 3) ? (45 + u) : (64 + u))   // scratch 67..70
                                    : (24 + 7 * (quad - 1) + u);
        featA[cell * 72 + dst] = v;
      }
    }

    // ================= L1: 12 MFMA, N=96 =================
    {
      const f16x8 A1a = *(const f16x8*)&featA[cell * 72 + quad * 8];
      const f16x8 A1b = *(const f16x8*)&featA[cell * 72 + quad * 8 + 32];
      #pragma unroll
      for (int nt = 0; nt < 6; ++nt) {
        f32x4 acc = {bias1v[nt], bias1v[nt], bias1v[nt], bias1v[nt]};
        acc = __builtin_amdgcn_mfma_f32_16x16x32_f16(A1a, B1[nt][0], acc, 0, 0, 0);
        acc = __builtin_amdgcn_mfma_f32_16x16x32_f16(A1b, B1[nt][1], acc, 0, 0, 0);
        #pragma unroll
        for (int r = 0; r < 4; ++r)
          h1A[(16 * w + quad * 4 + r) * 104 + 16 * nt + lam] = (_Float16)fast_tanh(acc[r]);
      }
    }

    // ================= L2: 6 MFMA, N=24(+pad) =================
    {
      f16x8 A2[3];
      #pragma unroll
      for (int kt = 0; kt < 3; ++kt)
        A2[kt] = *(const f16x8*)&h1A[cell * 104 + quad * 8 + 32 * kt];
      #pragma unroll
      for (int nt = 0; nt < 2; ++nt) {
        f32x4 acc = {bias2v[nt], bias2v[nt], bias2v[nt], bias2v[nt]};
        acc = __builtin_amdgcn_mfma_f32_16x16x32_f16(A2[0], B2[nt][0], acc, 0, 0, 0);
        acc = __builtin_amdgcn_mfma_f32_16x16x32_f16(A2[1], B2[nt][1], acc, 0, 0, 0);
        acc = __builtin_amdgcn_mfma_f32_16x16x32_f16(A2[2], B2[nt][2], acc, 0, 0, 0);
        const int n = 16 * nt + lam;
        if (n < 24) {
          #pragma unroll
          for (int r = 0; r < 4; ++r)
            h2A[(16 * w + quad * 4 + r) * 40 + n] = (_Float16)fast_tanh(acc[r]);
        }
      }
    }

    // ================= L3: 1 MFMA (K=24 pad32, N=12 pad16) + L4 butterfly ==
    {
      const f16x8 A3 = *(const f16x8*)&h2A[cell * 40 + quad * 8];
      f32x4 acc = {bias3v, bias3v, bias3v, bias3v};
      acc = __builtin_amdgcn_mfma_f32_16x16x32_f16(A3, B3, acc, 0, 0, 0);
      f32x4 vv;
      #pragma unroll
      for (int r = 0; r < 4; ++r)
        vv[r] = (lam < 12 ? fast_tanh(acc[r]) : 0.f) * w4v;
      #pragma unroll
      for (int mask = 1; mask < 16; mask <<= 1) {
        #pragma unroll
        for (int r = 0; r < 4; ++r) vv[r] += __shfl_xor(vv[r], mask, 64);
      }
      if (lam < 4) {   // lane (quad, lam) publishes cell 16w + quad*4 + lam
        const float sv = (lam == 0) ? vv[0] : (lam == 1) ? vv[1] : (lam == 2) ? vv[2] : vv[3];
        p4L[16 * w + quad * 4 + lam] = sv;
      }
    }

    // ================= finalize (quad 0 owner lanes, in-wave) =============
    if (quad == 0 && active) {
      const float s = p4L[cell] + b4v;
      const float pred = fast_tanh(s);
      const float d = xl4[3] - pred;                 // f32 target from regs
      ringH[(i & 63) * RW + 3 + j] = (_Float16)d;
      sumsq += d * d;
    }
    __syncthreads();   // the ONLY barrier: ring cross-wave visibility
  }

  // sumsq lives in quad-0 lanes; reduce wave then block
  #pragma unroll
  for (int off = 32; off >= 1; off >>= 1)
    sumsq += __shfl_down(sumsq, off);
  if (lane == 0) wsum[w] = sumsq;
  __syncthreads();
  if (tid == 0) ws[blockIdx.x] = wsum[0] + wsum[1] + wsum[2];
}

__global__ void finalize_kernel(const float* __restrict__ ws, float* __restrict__ out) {
  if (threadIdx.x == 0) {
    float s = 0.0f;
    #pragma unroll
    for (int p = 0; p < NPLANES; ++p) s += ws[p];
    out[0] = sqrtf(s / 875520.0f);   // b*c*(h-2)*w = 8*3*190*192
  }
}

extern "C" void kernel_launch(void* const* d_in, const int* in_sizes, int n_in,
                              void* d_out, int out_size, void* d_ws, size_t ws_size,
                              hipStream_t stream) {
  (void)in_sizes; (void)n_in; (void)out_size; (void)ws_size;
  const float* x  = (const float*)d_in[0];
  const float* W1 = (const float*)d_in[1];
  const float* b1 = (const float*)d_in[2];
  const float* W2 = (const float*)d_in[3];
  const float* b2 = (const float*)d_in[4];
  const float* W3 = (const float*)d_in[5];
  const float* b3 = (const float*)d_in[6];
  const float* W4 = (const float*)d_in[7];
  const float* b4 = (const float*)d_in[8];
  float* ws = (float*)d_ws;

  codec_kernel<<<NPLANES, 192, 0, stream>>>(x, W1, b1, W2, b2, W3, b3, W4, b4, ws);
  finalize_kernel<<<1, 64, 0, stream>>>(ws, (float*)d_out);
}

// Round 10
// 2410.004 us; speedup vs baseline: 1.4381x; 1.0140x over previous
//
#include <hip/hip_runtime.h>

#define NPLANES 24
#define IMG 192
#define RW 194        // f16 ring stride in halfs; addr col = 3 + delta-col
#define TSTEPS 926    // wavefront t = 4*i + j

typedef _Float16 h2v   __attribute__((ext_vector_type(2)));
typedef _Float16 f16x8 __attribute__((ext_vector_type(8)));
typedef float    f32x4 __attribute__((ext_vector_type(4)));
typedef __fp16   fp16x2 __attribute__((ext_vector_type(2)));

__device__ __forceinline__ h2v pk(float a, float b) {
  union { fp16x2 p; h2v h; } u;
  u.p = __builtin_amdgcn_cvt_pkrtz(a, b);
  return u.h;
}
__device__ __forceinline__ float fast_tanh(float x) {
  float e = __expf(2.0f * x);
  return 1.0f - 2.0f / (e + 1.0f);
}

// One block per plane, 192 threads = 3 waves. NO per-step __syncthreads:
// the only cross-wave state is the delta ring; waves sync point-to-point via
// LDS step counters (wave w spins until wave w-1 finished step t-1, acquire/
// release). Everything else (featA/h1A/h2A) is produced+consumed in-wave
// (DS pipe is in-order per wave). Wave w owns cells 16w..16w+15 (slot = i mod 48)
// and runs the whole pipeline: build -> L1 (12 MFMA) -> L2 (6 MFMA, K-split)
// -> L3 (1 MFMA) -> L4 (shfl butterfly + select) -> delta -> ring.
// x-window prefetched into regs one step ahead (incl. cold-start at j==-1);
// same-row last3 deltas kept in regs.
__launch_bounds__(192)
__global__ void codec_kernel(const float* __restrict__ x,
                             const float* __restrict__ W1g, const float* __restrict__ b1g,
                             const float* __restrict__ W2g, const float* __restrict__ b2g,
                             const float* __restrict__ W3g, const float* __restrict__ b3g,
                             const float* __restrict__ W4g, const float* __restrict__ b4g,
                             float* __restrict__ ws)
{
  __shared__ _Float16 ringH[64 * RW];   // f16 deltas; cols 0..2 & >=189 stay 0
  __shared__ _Float16 featA[48 * 72];   // [cell][48 feat | 16 ZERO K-pad | 8 pad]
  __shared__ _Float16 h1A  [48 * 104];  // [cell][96 + pad]
  __shared__ _Float16 h2A  [48 * 40];   // [cell][24 + 8 ZERO K-pad + 8 pad]
  __shared__ _Float16 w1B  [96 * 72];
  __shared__ _Float16 w2B  [32 * 104];
  __shared__ _Float16 w3B  [16 * 32];
  __shared__ float    b1L[96], b2L[24], b3L[16], w4F[16], b4L[1];
  __shared__ int      ctrL[4];
  __shared__ float    wsum[3];

  const int tid  = threadIdx.x;          // 0..191
  const int lane = tid & 63;
  const int w    = __builtin_amdgcn_readfirstlane(tid >> 6);   // wave 0..2
  const int lam  = lane & 15;
  const int quad = lane >> 4;
  const int cell = 16 * w + lam;
  const float* __restrict__ xp = x + (size_t)blockIdx.x * (IMG * IMG);

  // ---- one-time init ----
  { unsigned* z = (unsigned*)ringH; for (int u = tid; u < 64 * RW / 2;  u += 192) z[u] = 0; }
  { unsigned* z = (unsigned*)featA; for (int u = tid; u < 48 * 72 / 2;  u += 192) z[u] = 0; }
  { unsigned* z = (unsigned*)h1A;   for (int u = tid; u < 48 * 104 / 2; u += 192) z[u] = 0; }
  { unsigned* z = (unsigned*)h2A;   for (int u = tid; u < 48 * 40 / 2;  u += 192) z[u] = 0; }
  for (int u = tid; u < 96 * 72; u += 192) {
    int n = u / 72, k = u - n * 72;
    w1B[u] = (k < 48) ? (_Float16)W1g[k * 96 + n] : (_Float16)0.f;
  }
  for (int u = tid; u < 32 * 104; u += 192) {
    int n = u / 104, k = u - n * 104;
    w2B[u] = (n < 24 && k < 96) ? (_Float16)W2g[k * 24 + n] : (_Float16)0.f;
  }
  for (int u = tid; u < 16 * 32; u += 192) {
    int n = u / 32, k = u - n * 32;
    w3B[u] = (n < 12 && k < 24) ? (_Float16)W3g[k * 12 + n] : (_Float16)0.f;
  }
  for (int u = tid; u < 96; u += 192) b1L[u] = b1g[u];
  if (tid < 24) b2L[tid] = b2g[tid];
  if (tid < 16) b3L[tid] = (tid < 12) ? b3g[tid] : 0.f;
  if (tid < 16) w4F[tid] = (tid < 12) ? W4g[tid] : 0.f;
  if (tid == 0) b4L[0] = b4g[0];
  if (tid < 4)  ctrL[tid] = -1;
  __syncthreads();

  // ---- persistent weight fragments (loaded ONCE into VGPRs) ----
  f16x8 B1[6][2], B2[2][3], B3;
  float bias1v[6], bias2v[2];
  #pragma unroll
  for (int nt = 0; nt < 6; ++nt) {
    #pragma unroll
    for (int kt = 0; kt < 2; ++kt)
      B1[nt][kt] = *(const f16x8*)&w1B[(16 * nt + lam) * 72 + quad * 8 + 32 * kt];
    bias1v[nt] = b1L[16 * nt + lam];
  }
  #pragma unroll
  for (int nt = 0; nt < 2; ++nt) {
    #pragma unroll
    for (int kt = 0; kt < 3; ++kt)
      B2[nt][kt] = *(const f16x8*)&w2B[(16 * nt + lam) * 104 + quad * 8 + 32 * kt];
    bias2v[nt] = (16 * nt + lam < 24) ? b2L[16 * nt + lam] : 0.f;
  }
  B3 = *(const f16x8*)&w3B[lam * 32 + quad * 8];
  const float bias3v = b3L[lam];
  const float w4v    = w4F[lam];
  const float b4v    = b4L[0];

  // quad0 per-lane state
  float xw[3][7], xl3[3], xt = 0.f;    // sliding x-window, left ctx, target
  float px0 = 0.f, px1 = 0.f, px2 = 0.f, px3 = 0.f;  // prefetch for j+1
  float dl1 = 0.f, dl2 = 0.f, dl3 = 0.f;             // last3 own deltas
  bool  wp = false;                    // window prefetched for next row start
  float sumsq = 0.0f;

  const int prodw = (w == 0) ? 2 : w - 1;   // producer wave for ring rows above

  for (int t = 0; t < TSTEPS; ++t) {
    const int i_min = (t <= 185) ? 0 : ((t - 182) >> 2);
    int i_max = t >> 2; if (i_max > 185) i_max = 185;
    const int k48 = (i_min - cell + 47) / 48;
    const int i = cell + 48 * k48;
    const bool active = (i <= i_max);
    const int j = t - 4 * i;

    // ---- build x-part + last3 (quad0, in-wave) ----
    if (quad == 0 && active) {
      if (j == 0) {
        if (!wp) {                       // only t==0 cell 0 hits this cold path
          const float* xrow = xp + i * IMG;
          #pragma unroll
          for (int r = 0; r < 3; ++r)
            #pragma unroll
            for (int c = 0; c < 7; ++c) xw[r][c] = xrow[r * IMG + c];
          #pragma unroll
          for (int c = 0; c < 3; ++c) xl3[c] = xrow[3 * IMG + c];
          xt = xrow[3 * IMG + 3];
        }
        wp = false;
        dl1 = dl2 = dl3 = 0.f;
      } else {                           // slide using prefetched px
        #pragma unroll
        for (int r = 0; r < 3; ++r) {
          #pragma unroll
          for (int c = 0; c < 6; ++c) xw[r][c] = xw[r][c + 1];
        }
        xw[0][6] = px0; xw[1][6] = px1; xw[2][6] = px2;
        xl3[0] = xl3[1]; xl3[1] = xl3[2]; xl3[2] = xt;
        xt = px3;
      }
      float fx[24];
      #pragma unroll
      for (int r = 0; r < 3; ++r)
        #pragma unroll
        for (int c = 0; c < 7; ++c) fx[7 * r + c] = xw[r][c];
      fx[21] = xl3[0]; fx[22] = xl3[1]; fx[23] = xl3[2];
      union { h2v p[12]; float4 v[3]; } fb;
      #pragma unroll
      for (int q = 0; q < 12; ++q) fb.p[q] = pk(fx[2 * q], fx[2 * q + 1]);
      #pragma unroll
      for (int q = 0; q < 3; ++q)
        *(float4*)&featA[cell * 72 + 8 * q] = fb.v[q];
      featA[cell * 72 + 45] = (_Float16)dl3;
      featA[cell * 72 + 46] = (_Float16)dl2;
      featA[cell * 72 + 47] = (_Float16)dl1;
    }

    // ---- old taps (rows i-3, i-2): data >=5 steps old -> safe PRE-spin ----
    if ((quad == 1 || quad == 2) && active) {
      const int roff = quad - 4;               // q1 -> -3, q2 -> -2
      const int base = ((i + roff) & 63) * RW + j;
      const int dstb = cell * 72 + 24 + 7 * (quad - 1);
      #pragma unroll
      for (int u = 0; u < 7; ++u) featA[dstb + u] = ringH[base + u];
    }

    // ---- prefetch globals (latency hidden until next iteration) ----
    if (quad == 0) {
      if (active && j < 185) {
        const float* xrow = xp + i * IMG + j;
        px0 = xrow[7];
        px1 = xrow[IMG + 7];
        px2 = xrow[2 * IMG + 7];
        px3 = xrow[3 * IMG + 4];
      } else if (!active && i <= 185 && j == -1) {   // cold-start next row
        const float* xrow = xp + i * IMG;
        #pragma unroll
        for (int r = 0; r < 3; ++r)
          #pragma unroll
          for (int c = 0; c < 7; ++c) xw[r][c] = xrow[r * IMG + c];
        #pragma unroll
        for (int c = 0; c < 3; ++c) xl3[c] = xrow[3 * IMG + c];
        xt = xrow[3 * IMG + 3];
        wp = true;
      }
    }

    // ---- point-to-point sync: ring rows above from wave w-1, step t-1 ----
    if (t > 0) {
      while (__hip_atomic_load(&ctrL[prodw], __ATOMIC_ACQUIRE,
                               __HIP_MEMORY_SCOPE_WORKGROUP) < t - 1) { }
    }

    // ---- fresh taps (row i-1, includes step t-1 data) ----
    if (quad == 3 && active) {
      const int base = ((i - 1) & 63) * RW + j;
      const int dstb = cell * 72 + 38;
      #pragma unroll
      for (int u = 0; u < 7; ++u) featA[dstb + u] = ringH[base + u];
    }

    // ---- L1: 12 MFMA, N=96 ----
    {
      const f16x8 A1a = *(const f16x8*)&featA[cell * 72 + quad * 8];
      const f16x8 A1b = *(const f16x8*)&featA[cell * 72 + quad * 8 + 32];
      #pragma unroll
      for (int nt = 0; nt < 6; ++nt) {
        f32x4 acc = {bias1v[nt], bias1v[nt], bias1v[nt], bias1v[nt]};
        acc = __builtin_amdgcn_mfma_f32_16x16x32_f16(A1a, B1[nt][0], acc, 0, 0, 0);
        acc = __builtin_amdgcn_mfma_f32_16x16x32_f16(A1b, B1[nt][1], acc, 0, 0, 0);
        #pragma unroll
        for (int r = 0; r < 4; ++r)
          h1A[(16 * w + quad * 4 + r) * 104 + 16 * nt + lam] = (_Float16)fast_tanh(acc[r]);
      }
    }

    // ---- L2: K-split into 3 independent MFMAs ----
    {
      f16x8 A2[3];
      #pragma unroll
      for (int kt = 0; kt < 3; ++kt)
        A2[kt] = *(const f16x8*)&h1A[cell * 104 + quad * 8 + 32 * kt];
      #pragma unroll
      for (int nt = 0; nt < 2; ++nt) {
        f32x4 za = {bias2v[nt], bias2v[nt], bias2v[nt], bias2v[nt]};
        f32x4 zb = {0.f, 0.f, 0.f, 0.f};
        f32x4 zc = {0.f, 0.f, 0.f, 0.f};
        za = __builtin_amdgcn_mfma_f32_16x16x32_f16(A2[0], B2[nt][0], za, 0, 0, 0);
        zb = __builtin_amdgcn_mfma_f32_16x16x32_f16(A2[1], B2[nt][1], zb, 0, 0, 0);
        zc = __builtin_amdgcn_mfma_f32_16x16x32_f16(A2[2], B2[nt][2], zc, 0, 0, 0);
        const int n = 16 * nt + lam;
        if (n < 24) {
          #pragma unroll
          for (int r = 0; r < 4; ++r)
            h2A[(16 * w + quad * 4 + r) * 40 + n] =
                (_Float16)fast_tanh(za[r] + zb[r] + zc[r]);
        }
      }
    }

    // ---- L3: 1 MFMA + L4 butterfly + select (no LDS round-trip) ----
    float psum;
    {
      const f16x8 A3 = *(const f16x8*)&h2A[cell * 40 + quad * 8];
      f32x4 acc = {bias3v, bias3v, bias3v, bias3v};
      acc = __builtin_amdgcn_mfma_f32_16x16x32_f16(A3, B3, acc, 0, 0, 0);
      f32x4 vv;
      #pragma unroll
      for (int r = 0; r < 4; ++r) vv[r] = fast_tanh(acc[r]) * w4v;  // w4v=0 pads
      #pragma unroll
      for (int mask = 1; mask < 16; mask <<= 1) {
        #pragma unroll
        for (int r = 0; r < 4; ++r) vv[r] += __shfl_xor(vv[r], mask, 64);
      }
      // lane needs vv[lam&3] from quad (lam>>2): cell 16w+lam sum
      const float selLo = (lam & 1) ? vv[1] : vv[0];
      const float selHi = (lam & 1) ? vv[3] : vv[2];
      const float sel   = (lam & 2) ? selHi : selLo;
      const int src = ((lam >> 2) << 4) | (lam & 3);
      psum = __shfl(sel, src, 64);
    }

    // ---- finalize (quad0): delta, ring write, last3, sumsq ----
    if (quad == 0 && active) {
      const float pred = fast_tanh(psum + b4v);
      const float d = xt - pred;
      ringH[(i & 63) * RW + 3 + j] = (_Float16)d;
      dl3 = dl2; dl2 = dl1; dl1 = d;
      sumsq += d * d;
    }

    // ---- publish step t (release: orders ring writes before counter) ----
    if (lane == 0)
      __hip_atomic_store(&ctrL[w], t, __ATOMIC_RELEASE, __HIP_MEMORY_SCOPE_WORKGROUP);
  }

  // reduce sumsq (only quad0 lanes nonzero)
  #pragma unroll
  for (int off = 32; off >= 1; off >>= 1)
    sumsq += __shfl_down(sumsq, off);
  if (lane == 0) wsum[w] = sumsq;
  __syncthreads();
  if (tid == 0) ws[blockIdx.x] = wsum[0] + wsum[1] + wsum[2];
}

__global__ void finalize_kernel(const float* __restrict__ ws, float* __restrict__ out) {
  if (threadIdx.x == 0) {
    float s = 0.0f;
    #pragma unroll
    for (int p = 0; p < NPLANES; ++p) s += ws[p];
    out[0] = sqrtf(s / 875520.0f);   // b*c*(h-2)*w = 8*3*190*192
  }
}

extern "C" void kernel_launch(void* const* d_in, const int* in_sizes, int n_in,
                              void* d_out, int out_size, void* d_ws, size_t ws_size,
                              hipStream_t stream) {
  (void)in_sizes; (void)n_in; (void)out_size; (void)ws_size;
  const float* x  = (const float*)d_in[0];
  const float* W1 = (const float*)d_in[1];
  const float* b1 = (const float*)d_in[2];
  const float* W2 = (const float*)d_in[3];
  const float* b2 = (const float*)d_in[4];
  const float* W3 = (const float*)d_in[5];
  const float* b3 = (const float*)d_in[6];
  const float* W4 = (const float*)d_in[7];
  const float* b4 = (const float*)d_in[8];
  float* ws = (float*)d_ws;

  codec_kernel<<<NPLANES, 192, 0, stream>>>(x, W1, b1, W2, b2, W3, b3, W4, b4, ws);
  finalize_kernel<<<1, 64, 0, stream>>>(ws, (float*)d_out);
}